// Round 11
// baseline (132.584 us; speedup 1.0000x reference)
//
#include <hip/hip_runtime.h>
#include <cstdint>
#include <cstddef>

#define HIDDEN 1024
#define BATCH 4
#define SEQ 4096
#define M_ROWS (BATCH * SEQ)   // 16384
#define K_DIM 1024
#define SUBCHUNK 32
#define NSUB (SEQ / SUBCHUNK)  // 128

typedef __bf16 bf16_t;
typedef __bf16 v8bf __attribute__((ext_vector_type(8)));
typedef float v4f __attribute__((ext_vector_type(4)));

__device__ __forceinline__ unsigned short f32_to_bf16(float f) {
  unsigned int u = __float_as_uint(f);
  u += 0x7fffu + ((u >> 16) & 1u);   // round-to-nearest-even
  return (unsigned short)(u >> 16);
}
__device__ __forceinline__ float bf16_to_f32(unsigned short u) {
  return __uint_as_float((unsigned int)u << 16);
}

// ---- Merged convert: X fp32->bf16 (blocks 0..16383) and
//      Wb = (W0+W1)/8 | W1 | W2 as bf16 (blocks 16384..19455).
//      Block 0 also zeroes the gemm_f sync flags (stream-ordered before use).
__global__ void convert_kernel(const float* __restrict__ X,
                               const float* __restrict__ W0,
                               const float* __restrict__ W1,
                               const float* __restrict__ W2,
                               unsigned short* __restrict__ Xb,
                               unsigned short* __restrict__ Wb,
                               int* __restrict__ flags) {
  int bx = blockIdx.x;
  if (bx == 0 && threadIdx.x == 0) { flags[0] = 0; flags[1] = 0; }
  if (bx < 16384) {
    int i = bx * 256 + threadIdx.x;
    float4 f = ((const float4*)X)[i];
    ushort4 u;
    u.x = f32_to_bf16(f.x); u.y = f32_to_bf16(f.y);
    u.z = f32_to_bf16(f.z); u.w = f32_to_bf16(f.w);
    ((ushort4*)Xb)[i] = u;
  } else {
    int i = (bx - 16384) * 256 + threadIdx.x;
    int mat = i >> 18;
    int off = i & 0x3FFFF;
    float4 f;
    if (mat == 0) {
      float4 a = ((const float4*)W0)[off];
      float4 b = ((const float4*)W1)[off];
      f.x = (a.x + b.x) * 0.125f; f.y = (a.y + b.y) * 0.125f;
      f.z = (a.z + b.z) * 0.125f; f.w = (a.w + b.w) * 0.125f;
    } else {
      const float* src = (mat == 1) ? W1 : W2;
      f = ((const float4*)src)[off];
    }
    ushort4 u;
    u.x = f32_to_bf16(f.x); u.y = f32_to_bf16(f.y);
    u.z = f32_to_bf16(f.z); u.w = f32_to_bf16(f.w);
    ((ushort4*)Wb)[i] = u;
  }
}

// Lq layout (L buffer): quad (4 bf16) at ushort4 index ((gfb*16+slot)*512+thr)
// — 64-lane x 8B contiguous 512B bursts on both writer and reader sides.

// ============================================================================
// gemm_s: S = X @ W01^T, 256x256 tile, BK=64, 8 waves (2Mx4N), 8-phase
// counted-vmcnt schedule (R4-verified), fused in-subchunk-cummax epilogue
// writing Lq + cmax (compact burst at exit, R2 rule).
// ============================================================================
__global__ __launch_bounds__(512, 2) void gemm_s_kernel(
    const bf16_t* __restrict__ A, const bf16_t* __restrict__ B,
    unsigned short* __restrict__ Lp, float* __restrict__ cmax) {
  extern __shared__ __align__(16) char smem[];   // 131072 B

  const int tid = threadIdx.x;
  const int wave = tid >> 6;     // 0..7
  const int lane = tid & 63;
  const int quad = lane >> 4;    // 0..3
  const int r16 = lane & 15;
  const int wr = wave >> 2;      // 0..1 -> 128-row half
  const int wc = wave & 3;       // 0..3 -> 64-col quarter

  // Bijective XCD swizzle: 256 blocks = 8 XCDs x 32
  const int orig = (int)blockIdx.x;
  const int swz = (orig & 7) * 32 + (orig >> 3);
  const int bx = swz & 3;        // n-tile (4)
  const int mt = swz >> 2;       // m-tile (64)
  const int mtile0 = mt * 256;
  const int nbase = bx * 256;

  const int l3 = lane >> 3;
  const int lc = lane & 7;
  const size_t laneOff = (size_t)l3 * K_DIM + (size_t)((lc ^ l3) << 3);
  const bf16_t* Ag = A + (size_t)(mtile0 + wave * 8) * K_DIM + laneOff;
  const bf16_t* Bg = B + (size_t)(nbase + wave * 8) * K_DIM + laneOff;

  const int aRow = (wr * 128 + r16) * 128;   // bytes (row stride 128B)
  const int bRow = (wc * 64 + r16) * 128;
  const int cxor = (r16 & 7) * 16;
  const int qx = quad * 16;

  v4f acc[8][4];
#pragma unroll
  for (int i = 0; i < 8; ++i)
#pragma unroll
    for (int j = 0; j < 4; ++j) acc[i][j] = (v4f)(0.0f);

  v8bf afr[4];
  v8bf bfr[4][2];

#define STG_A(d, q, kt) __builtin_amdgcn_global_load_lds( \
    (__attribute__((address_space(1))) void*)(Ag + (size_t)(q) * (64 * K_DIM) + (size_t)(kt) * 64), \
    (__attribute__((address_space(3))) void*)(smem + (d) * 32768 + (q) * 8192 + wave * 1024), 16, 0, 0)
#define STG_B(d, q, kt) __builtin_amdgcn_global_load_lds( \
    (__attribute__((address_space(1))) void*)(Bg + (size_t)(q) * (64 * K_DIM) + (size_t)(kt) * 64), \
    (__attribute__((address_space(3))) void*)(smem + 65536 + (d) * 32768 + (q) * 8192 + wave * 1024), 16, 0, 0)
#define LDA(d, i, kk) (*(const v8bf*)(smem + (d) * 32768 + aRow + (i) * 2048 + (((kk) * 64 + qx) ^ cxor)))
#define LDB(d, j, kk) (*(const v8bf*)(smem + 65536 + (d) * 32768 + bRow + (j) * 2048 + (((kk) * 64 + qx) ^ cxor)))
#define RD_A(d, ih, kk) { _Pragma("unroll") for (int ii = 0; ii < 4; ++ii) afr[ii] = LDA(d, (ih) * 4 + ii, kk); }
#define RD_B(d, kk) { _Pragma("unroll") for (int j = 0; j < 4; ++j) bfr[j][kk] = LDB(d, j, kk); }
#define MM(ih, kk) \
  __builtin_amdgcn_s_barrier(); \
  asm volatile("s_waitcnt lgkmcnt(0)" ::: "memory"); \
  __builtin_amdgcn_s_setprio(1); \
  { _Pragma("unroll") for (int ii = 0; ii < 4; ++ii) { _Pragma("unroll") for (int j = 0; j < 4; ++j) \
      acc[(ih) * 4 + ii][j] = __builtin_amdgcn_mfma_f32_16x16x32_bf16(afr[ii], bfr[j][(kk)], acc[(ih) * 4 + ii][j], 0, 0, 0); } } \
  __builtin_amdgcn_s_setprio(0);
#define BAR() __builtin_amdgcn_s_barrier()
#define WAITV(n) asm volatile("s_waitcnt vmcnt(" #n ")" ::: "memory")

  // ---- Prologue: tile0 full -> buf0 (8 oldest), tile1 partial -> buf1 (4) ----
  STG_A(0, 0, 0); STG_A(0, 1, 0); STG_A(0, 2, 0); STG_A(0, 3, 0);
  STG_B(0, 0, 0); STG_B(0, 1, 0); STG_B(0, 2, 0); STG_B(0, 3, 0);
  STG_A(1, 0, 1); STG_A(1, 2, 1); STG_B(1, 0, 1); STG_B(1, 1, 1);
  WAITV(4);
  BAR();

  for (int it = 0; it < 7; ++it) {
    const int t1 = 2 * it + 1, t2 = t1 + 1, t3 = t1 + 2;
    RD_A(0, 0, 0); RD_B(0, 0);
    STG_B(1, 2, t1); STG_B(1, 3, t1);
    MM(0, 0); BAR();
    RD_B(0, 1); RD_A(0, 0, 1);
    STG_A(1, 1, t1); STG_A(1, 3, t1);
    MM(0, 1); BAR();
    RD_A(0, 1, 0);
    STG_A(0, 0, t2); STG_A(0, 2, t2);
    MM(1, 0); BAR();
    RD_A(0, 1, 1);
    STG_B(0, 0, t2); STG_B(0, 1, t2);
    MM(1, 1); WAITV(4); BAR();
    RD_A(1, 0, 0); RD_B(1, 0);
    STG_B(0, 2, t2); STG_B(0, 3, t2);
    MM(0, 0); BAR();
    RD_B(1, 1); RD_A(1, 0, 1);
    STG_A(0, 1, t2); STG_A(0, 3, t2);
    MM(0, 1); BAR();
    RD_A(1, 1, 0);
    STG_A(1, 0, t3); STG_A(1, 2, t3);
    MM(1, 0); BAR();
    RD_A(1, 1, 1);
    STG_B(1, 0, t3); STG_B(1, 1, t3);
    MM(1, 1); WAITV(4); BAR();
  }
  // ---- Tail: tiles 14 (buf0), 15 (buf1) ----
  RD_A(0, 0, 0); RD_B(0, 0);
  STG_B(1, 2, 15); STG_B(1, 3, 15);
  MM(0, 0); BAR();
  RD_B(0, 1); RD_A(0, 0, 1);
  STG_A(1, 1, 15); STG_A(1, 3, 15);
  MM(0, 1); BAR();
  RD_A(0, 1, 0); MM(1, 0); BAR();
  RD_A(0, 1, 1); MM(1, 1); WAITV(0); BAR();
  RD_A(1, 0, 0); RD_B(1, 0); MM(0, 0); BAR();
  RD_B(1, 1); RD_A(1, 0, 1); MM(0, 1); BAR();
  RD_A(1, 1, 0); MM(1, 0); BAR();
  RD_A(1, 1, 1); MM(1, 1);

#undef STG_A
#undef STG_B
#undef LDA
#undef LDB
#undef RD_A
#undef RD_B
#undef MM
#undef BAR
#undef WAITV

  // ---- Fused cummax epilogue -> Lq (coalesced 8B quad stores). ----
  const int ncol0 = bx * 256;
  const int bidx = mtile0 >> 12;
  const int sub0 = (mtile0 & 4095) >> 5;
  ushort4* Lq4 = (ushort4*)Lp;
#pragma unroll
  for (int s = 0; s < 4; ++s) {
#pragma unroll
    for (int j = 0; j < 4; ++j) {
      float c0[4], c1[4];
      c0[0] = acc[s * 2][j][0];
      c1[0] = acc[s * 2 + 1][j][0];
#pragma unroll
      for (int r = 1; r < 4; ++r) {
        c0[r] = fmaxf(c0[r - 1], acc[s * 2][j][r]);
        c1[r] = fmaxf(c1[r - 1], acc[s * 2 + 1][j][r]);
      }
      float t0 = c0[3], t1 = c1[3], u;
      u = __shfl_up(t0, 16); if (quad >= 1) t0 = fmaxf(t0, u);
      u = __shfl_up(t0, 32); if (quad >= 2) t0 = fmaxf(t0, u);
      u = __shfl_up(t1, 16); if (quad >= 1) t1 = fmaxf(t1, u);
      u = __shfl_up(t1, 32); if (quad >= 2) t1 = fmaxf(t1, u);
      float e0 = __shfl_up(t0, 16); if (quad == 0) e0 = -INFINITY;
      float e1 = __shfl_up(t1, 16); if (quad == 0) e1 = -INFINITY;
      float T0 = __shfl(t0, 48 + r16);
      float T1 = __shfl(t1, 48 + r16);
      const int gfb = mt * 8 + bx * 2 + (wc >> 1);
      const int thrC = (wr * 4 + (wc & 1) * 2 + (j >> 1)) * 64 + lane;
      ushort4 q0, q1;
      q0.x = f32_to_bf16(fmaxf(c0[0], e0));
      q0.y = f32_to_bf16(fmaxf(c0[1], e0));
      q0.z = f32_to_bf16(fmaxf(c0[2], e0));
      q0.w = f32_to_bf16(fmaxf(c0[3], e0));
      float f1 = fmaxf(e1, T0);
      q1.x = f32_to_bf16(fmaxf(c1[0], f1));
      q1.y = f32_to_bf16(fmaxf(c1[1], f1));
      q1.z = f32_to_bf16(fmaxf(c1[2], f1));
      q1.w = f32_to_bf16(fmaxf(c1[3], f1));
      Lq4[((size_t)gfb * 16 + (s * 2 + 0) * 2 + (j & 1)) * 512 + thrC] = q0;
      Lq4[((size_t)gfb * 16 + (s * 2 + 1) * 2 + (j & 1)) * 512 + thrC] = q1;
      if (quad == 0) {
        int sub = sub0 + wr * 4 + s;
        int col = ncol0 + wc * 64 + j * 16 + r16;
        cmax[((size_t)bidx * NSUB + sub) * HIDDEN + col] = fmaxf(T0, T1);
      }
    }
  }
}

// ============================================================================
// gemm_f: dual GEMM (C1, C2) + fused final epilogue.  Also absorbs the
// prefix-max pass: the first 64 blocks to start (device-atomic ticket — the
// claimants are executing blocks, so no dispatch-order assumption, no
// deadlock) compute a 64-col pmax slice on WAVE 0 ONLY before the prologue
// (vmcnt is per-wave; other waves' staging ledger untouched; wave 0 drains
// to vmcnt(0) before staging).  Epilogue: acquire-spin on done==64 (long
// satisfied after the ~30us K-loop), then read pmax.  Lq prefetched at the
// ledger-safe point (after the tail's final counted WAITV).
// ============================================================================
__global__ __launch_bounds__(512, 2) void gemm_f_kernel(
    const bf16_t* __restrict__ A, const bf16_t* __restrict__ B,
    const unsigned short* __restrict__ Lp, const float* __restrict__ cmax,
    float* __restrict__ pmax, int* __restrict__ flags,
    float* __restrict__ out) {
  extern __shared__ __align__(16) char smem[];   // 131072 B

  const int tid = threadIdx.x;
  const int wave = tid >> 6;     // 0..7
  const int lane = tid & 63;
  const int quad = lane >> 4;
  const int r16 = lane & 15;
  const int wr = wave >> 2;      // 0..1 -> 128-row half
  const int wc = wave & 3;       // 0..3 -> 32-col quarter

  // Bijective XCD swizzle: 512 blocks = 8 XCDs x 64
  const int orig = (int)blockIdx.x;
  const int swz = (orig & 7) * 64 + (orig >> 3);
  const int mt = swz >> 3;       // 0..63
  const int nt = swz & 7;        // 0..7
  const int mtile0 = mt * 256;
  const int ncol0 = nt * 128;

  // ---- Inline prefix-max slice (wave 0 of the first 64 claimants) ----
  if (wave == 0) {
    int ticket = 0;
    if (lane == 0)
      ticket = __hip_atomic_fetch_add(&flags[0], 1, __ATOMIC_RELAXED,
                                      __HIP_MEMORY_SCOPE_AGENT);
    ticket = __shfl(ticket, 0);
    if (ticket < 64) {
      const int pb = ticket >> 4;
      const int pcol = (ticket & 15) * 64 + lane;
      const float* cp = cmax + (size_t)pb * NSUB * HIDDEN + pcol;
      float* pp = pmax + (size_t)pb * NSUB * HIDDEN + pcol;
      float run = -INFINITY;
#pragma unroll 1
      for (int s0 = 0; s0 < NSUB; s0 += 16) {
        float v[16];
#pragma unroll
        for (int i = 0; i < 16; ++i) v[i] = cp[(size_t)(s0 + i) * HIDDEN];
#pragma unroll
        for (int i = 0; i < 16; ++i) {
          pp[(size_t)(s0 + i) * HIDDEN] = run;
          run = fmaxf(run, v[i]);
        }
      }
      asm volatile("s_waitcnt vmcnt(0)" ::: "memory");
      __threadfence();
      if (lane == 0)
        __hip_atomic_fetch_add(&flags[1], 1, __ATOMIC_RELEASE,
                               __HIP_MEMORY_SCOPE_AGENT);
    }
  }

  const int l3 = lane >> 3;
  const int lc = lane & 7;
  const size_t laneOff = (size_t)l3 * K_DIM + (size_t)((lc ^ l3) << 3);
  const bf16_t* Ag = A + (size_t)(mtile0 + wave * 8) * K_DIM + laneOff;
  const bf16_t* Bg1 = B + (size_t)(1024 + ncol0 + wave * 8) * K_DIM + laneOff;
  const bf16_t* Bg2 = B + (size_t)(2048 + ncol0 + wave * 8) * K_DIM + laneOff;

  const int aRow = (wr * 128 + r16) * 128;   // bytes
  const int bRow = (wc * 32 + r16) * 128;    // within 128-row B panel
  const int cxor = (r16 & 7) * 16;
  const int qx = quad * 16;

  v4f acc1[8][2], acc2[8][2];
#pragma unroll
  for (int i = 0; i < 8; ++i)
#pragma unroll
    for (int j = 0; j < 2; ++j) { acc1[i][j] = (v4f)(0.0f); acc2[i][j] = (v4f)(0.0f); }

  v8bf afr[4];
  v8bf b1fr[2][2], b2fr[2][2];

#define STG2_A(d, q, kt) __builtin_amdgcn_global_load_lds( \
    (__attribute__((address_space(1))) void*)(Ag + (size_t)(q) * (64 * K_DIM) + (size_t)(kt) * 64), \
    (__attribute__((address_space(3))) void*)(smem + (d) * 32768 + (q) * 8192 + wave * 1024), 16, 0, 0)
#define STG2_B1(d, q, kt) __builtin_amdgcn_global_load_lds( \
    (__attribute__((address_space(1))) void*)(Bg1 + (size_t)(q) * (64 * K_DIM) + (size_t)(kt) * 64), \
    (__attribute__((address_space(3))) void*)(smem + 65536 + (d) * 32768 + (q) * 8192 + wave * 1024), 16, 0, 0)
#define STG2_B2(d, q, kt) __builtin_amdgcn_global_load_lds( \
    (__attribute__((address_space(1))) void*)(Bg2 + (size_t)(q) * (64 * K_DIM) + (size_t)(kt) * 64), \
    (__attribute__((address_space(3))) void*)(smem + 65536 + (d) * 32768 + 16384 + (q) * 8192 + wave * 1024), 16, 0, 0)
#define LDA2(d, i, kk) (*(const v8bf*)(smem + (d) * 32768 + aRow + (i) * 2048 + (((kk) * 64 + qx) ^ cxor)))
#define LDB21(d, j, kk) (*(const v8bf*)(smem + 65536 + (d) * 32768 + bRow + (j) * 2048 + (((kk) * 64 + qx) ^ cxor)))
#define LDB22(d, j, kk) (*(const v8bf*)(smem + 65536 + (d) * 32768 + 16384 + bRow + (j) * 2048 + (((kk) * 64 + qx) ^ cxor)))
#define RD2_A(d, ih, kk) { _Pragma("unroll") for (int ii = 0; ii < 4; ++ii) afr[ii] = LDA2(d, (ih) * 4 + ii, kk); }
#define RD2_B(d, kk) { _Pragma("unroll") for (int j = 0; j < 2; ++j) { b1fr[j][kk] = LDB21(d, j, kk); b2fr[j][kk] = LDB22(d, j, kk); } }
#define MM2(ih, kk) \
  __builtin_amdgcn_s_barrier(); \
  asm volatile("s_waitcnt lgkmcnt(0)" ::: "memory"); \
  __builtin_amdgcn_s_setprio(1); \
  { _Pragma("unroll") for (int ii = 0; ii < 4; ++ii) { _Pragma("unroll") for (int j = 0; j < 2; ++j) { \
      acc1[(ih) * 4 + ii][j] = __builtin_amdgcn_mfma_f32_16x16x32_bf16(afr[ii], b1fr[j][(kk)], acc1[(ih) * 4 + ii][j], 0, 0, 0); \
      acc2[(ih) * 4 + ii][j] = __builtin_amdgcn_mfma_f32_16x16x32_bf16(afr[ii], b2fr[j][(kk)], acc2[(ih) * 4 + ii][j], 0, 0, 0); } } } \
  __builtin_amdgcn_s_setprio(0);
#define BAR() __builtin_amdgcn_s_barrier()
#define WAITV(n) asm volatile("s_waitcnt vmcnt(" #n ")" ::: "memory")

  // ---- Prologue ----
  STG2_A(0, 0, 0); STG2_A(0, 1, 0); STG2_A(0, 2, 0); STG2_A(0, 3, 0);
  STG2_B1(0, 0, 0); STG2_B1(0, 1, 0); STG2_B2(0, 0, 0); STG2_B2(0, 1, 0);
  STG2_A(1, 0, 1); STG2_A(1, 2, 1); STG2_B1(1, 0, 1); STG2_B1(1, 1, 1);
  WAITV(4);
  BAR();

  for (int it = 0; it < 7; ++it) {
    const int t1 = 2 * it + 1, t2 = t1 + 1, t3 = t1 + 2;
    RD2_A(0, 0, 0); RD2_B(0, 0);
    STG2_B2(1, 0, t1); STG2_B2(1, 1, t1);
    MM2(0, 0); BAR();
    RD2_B(0, 1); RD2_A(0, 0, 1);
    STG2_A(1, 1, t1); STG2_A(1, 3, t1);
    MM2(0, 1); BAR();
    RD2_A(0, 1, 0);
    STG2_A(0, 0, t2); STG2_A(0, 2, t2);
    MM2(1, 0); BAR();
    RD2_A(0, 1, 1);
    STG2_B1(0, 0, t2); STG2_B1(0, 1, t2);
    MM2(1, 1); WAITV(4); BAR();
    RD2_A(1, 0, 0); RD2_B(1, 0);
    STG2_B2(0, 0, t2); STG2_B2(0, 1, t2);
    MM2(0, 0); BAR();
    RD2_B(1, 1); RD2_A(1, 0, 1);
    STG2_A(0, 1, t2); STG2_A(0, 3, t2);
    MM2(0, 1); BAR();
    RD2_A(1, 1, 0);
    STG2_A(1, 0, t3); STG2_A(1, 2, t3);
    MM2(1, 0); BAR();
    RD2_A(1, 1, 1);
    STG2_B1(1, 0, t3); STG2_B1(1, 1, t3);
    MM2(1, 1); WAITV(4); BAR();
  }
  // ---- Tail ----
  RD2_A(0, 0, 0); RD2_B(0, 0);
  STG2_B2(1, 0, 15); STG2_B2(1, 1, 15);
  MM2(0, 0); BAR();
  RD2_B(0, 1); RD2_A(0, 0, 1);
  STG2_A(1, 1, 15); STG2_A(1, 3, 15);
  MM2(0, 1); BAR();
  RD2_A(0, 1, 0); MM2(1, 0); BAR();
  RD2_A(0, 1, 1); MM2(1, 1); WAITV(0); BAR();

  // Lq prefetch: after the LAST counted WAITV — no subsequent vmcnt wait
  // counts these, and they overlap the final 4 MFMA phases (~800 cy).
  const int gfb = mt * 8 + nt;
  const ushort4* Lq4 = (const ushort4*)Lp;
  ushort4 lfv[8][2];
#pragma unroll
  for (int i = 0; i < 8; ++i)
#pragma unroll
    for (int j = 0; j < 2; ++j)
      lfv[i][j] = Lq4[((size_t)gfb * 16 + i * 2 + j) * 512 + tid];

  RD2_A(1, 0, 0); RD2_B(1, 0); MM2(0, 0); BAR();
  RD2_B(1, 1); RD2_A(1, 0, 1); MM2(0, 1); BAR();
  RD2_A(1, 1, 0); MM2(1, 0); BAR();
  RD2_A(1, 1, 1); MM2(1, 1);

#undef STG2_A
#undef STG2_B1
#undef STG2_B2
#undef LDA2
#undef LDB21
#undef LDB22
#undef RD2_A
#undef RD2_B
#undef MM2
#undef BAR
#undef WAITV

  // ---- Wait for pmax complete (done==64), then fused final epilogue. ----
  if (tid == 0) {
    while (__hip_atomic_load(&flags[1], __ATOMIC_ACQUIRE,
                             __HIP_MEMORY_SCOPE_AGENT) < 64)
      __builtin_amdgcn_s_sleep(2);
  }
  __syncthreads();

  const int bidx = mtile0 >> 12;
  const int sub0 = (mtile0 & 4095) >> 5;
#pragma unroll
  for (int i = 0; i < 8; ++i) {
    const int subr = sub0 + wr * 4 + (i >> 1);
#pragma unroll
    for (int j = 0; j < 2; ++j) {
      const int col = ncol0 + wc * 32 + j * 16 + r16;
      const float pm = pmax[((size_t)bidx * NSUB + subr) * HIDDEN + col];
      const ushort4 q = lfv[i][j];
      const int row0 = mtile0 + wr * 128 + i * 16 + quad * 4;
      float m0 = fmaxf(pm, bf16_to_f32(q.x));
      float m1 = fmaxf(pm, bf16_to_f32(q.y));
      float m2 = fmaxf(pm, bf16_to_f32(q.z));
      float m3 = fmaxf(pm, bf16_to_f32(q.w));
      size_t idx = (size_t)row0 * HIDDEN + col;
      out[idx] = (m0 + acc2[i][j][0]) * m0 + acc1[i][j][0];
      out[idx + HIDDEN] = (m1 + acc2[i][j][1]) * m1 + acc1[i][j][1];
      out[idx + 2 * HIDDEN] = (m2 + acc2[i][j][2]) * m2 + acc1[i][j][2];
      out[idx + 3 * HIDDEN] = (m3 + acc2[i][j][3]) * m3 + acc1[i][j][3];
    }
  }
}

extern "C" void kernel_launch(void* const* d_in, const int* in_sizes, int n_in,
                              void* d_out, int out_size, void* d_ws, size_t ws_size,
                              hipStream_t stream) {
  const float* X = (const float*)d_in[0];
  const float* W0 = (const float*)d_in[1];
  const float* W1 = (const float*)d_in[2];
  const float* W2 = (const float*)d_in[3];
  float* out = (float*)d_out;

  char* ws = (char*)d_ws;
  unsigned short* Xb = (unsigned short*)ws;
  unsigned short* Wb = (unsigned short*)(ws + 33554432);
  unsigned short* Lp = (unsigned short*)(ws + 33554432 + 6291456);  // Lq
  int* flags = (int*)(ws + 2 * 33554432 + 6291456);  // dead C1p region
  float* cmax = (float*)(ws + 4 * 33554432 + 6291456);
  float* pmax = (float*)(ws + 4 * 33554432 + 6291456 + 2097152);

  convert_kernel<<<19456, 256, 0, stream>>>(X, W0, W1, W2, Xb, Wb, flags);

  gemm_s_kernel<<<256, 512, 131072, stream>>>((const bf16_t*)Xb, (const bf16_t*)Wb,
                                              Lp, cmax);

  // prefix pass is folded into gemm_f (first 64 claimant blocks, wave 0)
  gemm_f_kernel<<<512, 512, 131072, stream>>>((const bf16_t*)Xb, (const bf16_t*)Wb,
                                              Lp, cmax, pmax, flags, out);
}

// Round 12
// 130.472 us; speedup vs baseline: 1.0162x; 1.0162x over previous
//
#include <hip/hip_runtime.h>
#include <cstdint>
#include <cstddef>

#define HIDDEN 1024
#define BATCH 4
#define SEQ 4096
#define M_ROWS (BATCH * SEQ)   // 16384
#define K_DIM 1024
#define SUBCHUNK 32
#define NSUB (SEQ / SUBCHUNK)  // 128

typedef __bf16 bf16_t;
typedef __bf16 v8bf __attribute__((ext_vector_type(8)));
typedef float v4f __attribute__((ext_vector_type(4)));

__device__ __forceinline__ unsigned short f32_to_bf16(float f) {
  unsigned int u = __float_as_uint(f);
  u += 0x7fffu + ((u >> 16) & 1u);   // round-to-nearest-even
  return (unsigned short)(u >> 16);
}
__device__ __forceinline__ float bf16_to_f32(unsigned short u) {
  return __uint_as_float((unsigned int)u << 16);
}

// ---- Merged convert: X fp32->bf16 (blocks 0..16383) and
//      Wb = (W0+W1)/8 | W1 | W2 as bf16 (blocks 16384..19455) ----
__global__ void convert_kernel(const float* __restrict__ X,
                               const float* __restrict__ W0,
                               const float* __restrict__ W1,
                               const float* __restrict__ W2,
                               unsigned short* __restrict__ Xb,
                               unsigned short* __restrict__ Wb) {
  int bx = blockIdx.x;
  if (bx < 16384) {
    int i = bx * 256 + threadIdx.x;
    float4 f = ((const float4*)X)[i];
    ushort4 u;
    u.x = f32_to_bf16(f.x); u.y = f32_to_bf16(f.y);
    u.z = f32_to_bf16(f.z); u.w = f32_to_bf16(f.w);
    ((ushort4*)Xb)[i] = u;
  } else {
    int i = (bx - 16384) * 256 + threadIdx.x;
    int mat = i >> 18;
    int off = i & 0x3FFFF;
    float4 f;
    if (mat == 0) {
      float4 a = ((const float4*)W0)[off];
      float4 b = ((const float4*)W1)[off];
      f.x = (a.x + b.x) * 0.125f; f.y = (a.y + b.y) * 0.125f;
      f.z = (a.z + b.z) * 0.125f; f.w = (a.w + b.w) * 0.125f;
    } else {
      const float* src = (mat == 1) ? W1 : W2;
      f = ((const float4*)src)[off];
    }
    ushort4 u;
    u.x = f32_to_bf16(f.x); u.y = f32_to_bf16(f.y);
    u.z = f32_to_bf16(f.z); u.w = f32_to_bf16(f.w);
    ((ushort4*)Wb)[i] = u;
  }
}

// Lq layout (L buffer): quad (4 bf16) at ushort4 index ((gfb*16+slot)*512+thr)
// — 64-lane x 8B contiguous 512B bursts on both writer and reader sides.

// ============================================================================
// gemm_s: S = X @ W01^T, 256x256 tile, BK=64, 8 waves (2Mx4N), 8-phase
// counted-vmcnt schedule (R4-verified), fused in-subchunk-cummax epilogue
// writing Lq + cmax (compact burst at exit, R2 rule).
// ============================================================================
__global__ __launch_bounds__(512, 2) void gemm_s_kernel(
    const bf16_t* __restrict__ A, const bf16_t* __restrict__ B,
    unsigned short* __restrict__ Lp, float* __restrict__ cmax) {
  extern __shared__ __align__(16) char smem[];   // 131072 B

  const int tid = threadIdx.x;
  const int wave = tid >> 6;     // 0..7
  const int lane = tid & 63;
  const int quad = lane >> 4;    // 0..3
  const int r16 = lane & 15;
  const int wr = wave >> 2;      // 0..1 -> 128-row half
  const int wc = wave & 3;       // 0..3 -> 64-col quarter

  // Bijective XCD swizzle: 256 blocks = 8 XCDs x 32
  const int orig = (int)blockIdx.x;
  const int swz = (orig & 7) * 32 + (orig >> 3);
  const int bx = swz & 3;        // n-tile (4)
  const int mt = swz >> 2;       // m-tile (64)
  const int mtile0 = mt * 256;
  const int nbase = bx * 256;

  const int l3 = lane >> 3;
  const int lc = lane & 7;
  const size_t laneOff = (size_t)l3 * K_DIM + (size_t)((lc ^ l3) << 3);
  const bf16_t* Ag = A + (size_t)(mtile0 + wave * 8) * K_DIM + laneOff;
  const bf16_t* Bg = B + (size_t)(nbase + wave * 8) * K_DIM + laneOff;

  const int aRow = (wr * 128 + r16) * 128;   // bytes (row stride 128B)
  const int bRow = (wc * 64 + r16) * 128;
  const int cxor = (r16 & 7) * 16;
  const int qx = quad * 16;

  v4f acc[8][4];
#pragma unroll
  for (int i = 0; i < 8; ++i)
#pragma unroll
    for (int j = 0; j < 4; ++j) acc[i][j] = (v4f)(0.0f);

  v8bf afr[4];
  v8bf bfr[4][2];

#define STG_A(d, q, kt) __builtin_amdgcn_global_load_lds( \
    (__attribute__((address_space(1))) void*)(Ag + (size_t)(q) * (64 * K_DIM) + (size_t)(kt) * 64), \
    (__attribute__((address_space(3))) void*)(smem + (d) * 32768 + (q) * 8192 + wave * 1024), 16, 0, 0)
#define STG_B(d, q, kt) __builtin_amdgcn_global_load_lds( \
    (__attribute__((address_space(1))) void*)(Bg + (size_t)(q) * (64 * K_DIM) + (size_t)(kt) * 64), \
    (__attribute__((address_space(3))) void*)(smem + 65536 + (d) * 32768 + (q) * 8192 + wave * 1024), 16, 0, 0)
#define LDA(d, i, kk) (*(const v8bf*)(smem + (d) * 32768 + aRow + (i) * 2048 + (((kk) * 64 + qx) ^ cxor)))
#define LDB(d, j, kk) (*(const v8bf*)(smem + 65536 + (d) * 32768 + bRow + (j) * 2048 + (((kk) * 64 + qx) ^ cxor)))
#define RD_A(d, ih, kk) { _Pragma("unroll") for (int ii = 0; ii < 4; ++ii) afr[ii] = LDA(d, (ih) * 4 + ii, kk); }
#define RD_B(d, kk) { _Pragma("unroll") for (int j = 0; j < 4; ++j) bfr[j][kk] = LDB(d, j, kk); }
#define MM(ih, kk) \
  __builtin_amdgcn_s_barrier(); \
  asm volatile("s_waitcnt lgkmcnt(0)" ::: "memory"); \
  __builtin_amdgcn_s_setprio(1); \
  { _Pragma("unroll") for (int ii = 0; ii < 4; ++ii) { _Pragma("unroll") for (int j = 0; j < 4; ++j) \
      acc[(ih) * 4 + ii][j] = __builtin_amdgcn_mfma_f32_16x16x32_bf16(afr[ii], bfr[j][(kk)], acc[(ih) * 4 + ii][j], 0, 0, 0); } } \
  __builtin_amdgcn_s_setprio(0);
#define BAR() __builtin_amdgcn_s_barrier()
#define WAITV(n) asm volatile("s_waitcnt vmcnt(" #n ")" ::: "memory")

  // ---- Prologue: tile0 full -> buf0 (8 oldest), tile1 partial -> buf1 (4) ----
  STG_A(0, 0, 0); STG_A(0, 1, 0); STG_A(0, 2, 0); STG_A(0, 3, 0);
  STG_B(0, 0, 0); STG_B(0, 1, 0); STG_B(0, 2, 0); STG_B(0, 3, 0);
  STG_A(1, 0, 1); STG_A(1, 2, 1); STG_B(1, 0, 1); STG_B(1, 1, 1);
  WAITV(4);
  BAR();

  for (int it = 0; it < 7; ++it) {
    const int t1 = 2 * it + 1, t2 = t1 + 1, t3 = t1 + 2;
    RD_A(0, 0, 0); RD_B(0, 0);
    STG_B(1, 2, t1); STG_B(1, 3, t1);
    MM(0, 0); BAR();
    RD_B(0, 1); RD_A(0, 0, 1);
    STG_A(1, 1, t1); STG_A(1, 3, t1);
    MM(0, 1); BAR();
    RD_A(0, 1, 0);
    STG_A(0, 0, t2); STG_A(0, 2, t2);
    MM(1, 0); BAR();
    RD_A(0, 1, 1);
    STG_B(0, 0, t2); STG_B(0, 1, t2);
    MM(1, 1); WAITV(4); BAR();
    RD_A(1, 0, 0); RD_B(1, 0);
    STG_B(0, 2, t2); STG_B(0, 3, t2);
    MM(0, 0); BAR();
    RD_B(1, 1); RD_A(1, 0, 1);
    STG_A(0, 1, t2); STG_A(0, 3, t2);
    MM(0, 1); BAR();
    RD_A(1, 1, 0);
    STG_A(1, 0, t3); STG_A(1, 2, t3);
    MM(1, 0); BAR();
    RD_A(1, 1, 1);
    STG_B(1, 0, t3); STG_B(1, 1, t3);
    MM(1, 1); WAITV(4); BAR();
  }
  // ---- Tail: tiles 14 (buf0), 15 (buf1) ----
  RD_A(0, 0, 0); RD_B(0, 0);
  STG_B(1, 2, 15); STG_B(1, 3, 15);
  MM(0, 0); BAR();
  RD_B(0, 1); RD_A(0, 0, 1);
  STG_A(1, 1, 15); STG_A(1, 3, 15);
  MM(0, 1); BAR();
  RD_A(0, 1, 0); MM(1, 0); BAR();
  RD_A(0, 1, 1); MM(1, 1); WAITV(0); BAR();
  RD_A(1, 0, 0); RD_B(1, 0); MM(0, 0); BAR();
  RD_B(1, 1); RD_A(1, 0, 1); MM(0, 1); BAR();
  RD_A(1, 1, 0); MM(1, 0); BAR();
  RD_A(1, 1, 1); MM(1, 1);

#undef STG_A
#undef STG_B
#undef LDA
#undef LDB
#undef RD_A
#undef RD_B
#undef MM
#undef BAR
#undef WAITV

  // ---- Fused cummax epilogue -> Lq (coalesced 8B quad stores). ----
  const int ncol0 = bx * 256;
  const int bidx = mtile0 >> 12;
  const int sub0 = (mtile0 & 4095) >> 5;
  ushort4* Lq4 = (ushort4*)Lp;
#pragma unroll
  for (int s = 0; s < 4; ++s) {
#pragma unroll
    for (int j = 0; j < 4; ++j) {
      float c0[4], c1[4];
      c0[0] = acc[s * 2][j][0];
      c1[0] = acc[s * 2 + 1][j][0];
#pragma unroll
      for (int r = 1; r < 4; ++r) {
        c0[r] = fmaxf(c0[r - 1], acc[s * 2][j][r]);
        c1[r] = fmaxf(c1[r - 1], acc[s * 2 + 1][j][r]);
      }
      float t0 = c0[3], t1 = c1[3], u;
      u = __shfl_up(t0, 16); if (quad >= 1) t0 = fmaxf(t0, u);
      u = __shfl_up(t0, 32); if (quad >= 2) t0 = fmaxf(t0, u);
      u = __shfl_up(t1, 16); if (quad >= 1) t1 = fmaxf(t1, u);
      u = __shfl_up(t1, 32); if (quad >= 2) t1 = fmaxf(t1, u);
      float e0 = __shfl_up(t0, 16); if (quad == 0) e0 = -INFINITY;
      float e1 = __shfl_up(t1, 16); if (quad == 0) e1 = -INFINITY;
      float T0 = __shfl(t0, 48 + r16);
      float T1 = __shfl(t1, 48 + r16);
      const int gfb = mt * 8 + bx * 2 + (wc >> 1);
      const int thrC = (wr * 4 + (wc & 1) * 2 + (j >> 1)) * 64 + lane;
      ushort4 q0, q1;
      q0.x = f32_to_bf16(fmaxf(c0[0], e0));
      q0.y = f32_to_bf16(fmaxf(c0[1], e0));
      q0.z = f32_to_bf16(fmaxf(c0[2], e0));
      q0.w = f32_to_bf16(fmaxf(c0[3], e0));
      float f1 = fmaxf(e1, T0);
      q1.x = f32_to_bf16(fmaxf(c1[0], f1));
      q1.y = f32_to_bf16(fmaxf(c1[1], f1));
      q1.z = f32_to_bf16(fmaxf(c1[2], f1));
      q1.w = f32_to_bf16(fmaxf(c1[3], f1));
      Lq4[((size_t)gfb * 16 + (s * 2 + 0) * 2 + (j & 1)) * 512 + thrC] = q0;
      Lq4[((size_t)gfb * 16 + (s * 2 + 1) * 2 + (j & 1)) * 512 + thrC] = q1;
      if (quad == 0) {
        int sub = sub0 + wr * 4 + s;
        int col = ncol0 + wc * 64 + j * 16 + r16;
        cmax[((size_t)bidx * NSUB + sub) * HIDDEN + col] = fmaxf(T0, T1);
      }
    }
  }
}

// ---- Exclusive prefix-max over subchunks (L2-resident, 2 MB) ----
__global__ void prefix_kernel(const float* __restrict__ cmax,
                              float* __restrict__ pmax) {
  int col = blockIdx.x * 256 + threadIdx.x;
  int b = blockIdx.y;
  const float* cp = cmax + (size_t)b * NSUB * HIDDEN + col;
  float* pp = pmax + (size_t)b * NSUB * HIDDEN + col;
  float run = -INFINITY;
#pragma unroll 1
  for (int s0 = 0; s0 < NSUB; s0 += 16) {
    float v[16];
#pragma unroll
    for (int i = 0; i < 16; ++i) v[i] = cp[(size_t)(s0 + i) * HIDDEN];
#pragma unroll
    for (int i = 0; i < 16; ++i) {
      pp[(size_t)(s0 + i) * HIDDEN] = run;
      run = fmaxf(run, v[i]);
    }
  }
}

// ============================================================================
// gemm_f: dual GEMM (C1, C2) for the same 256x128 output region + fused
// final epilogue out = (max(pmax,L)+c2)*max(pmax,L)+c1.  R4-verified K-loop.
// Lq prefetched at the LEDGER-SAFE point: after the tail's final counted
// WAITV(0) — no subsequent vmcnt wait counts these loads, and their L2
// latency hides under the last 4 MFMA phases (the one isolated positive
// candidate from the R11 bundle; R7's variant failed because it sat AHEAD
// of tail STGs in the vmcnt FIFO).
// ============================================================================
__global__ __launch_bounds__(512, 2) void gemm_f_kernel(
    const bf16_t* __restrict__ A, const bf16_t* __restrict__ B,
    const unsigned short* __restrict__ Lp, const float* __restrict__ pmax,
    float* __restrict__ out) {
  extern __shared__ __align__(16) char smem[];   // 131072 B

  const int tid = threadIdx.x;
  const int wave = tid >> 6;     // 0..7
  const int lane = tid & 63;
  const int quad = lane >> 4;
  const int r16 = lane & 15;
  const int wr = wave >> 2;      // 0..1 -> 128-row half
  const int wc = wave & 3;       // 0..3 -> 32-col quarter

  // Bijective XCD swizzle: 512 blocks = 8 XCDs x 64
  const int orig = (int)blockIdx.x;
  const int swz = (orig & 7) * 64 + (orig >> 3);
  const int mt = swz >> 3;       // 0..63
  const int nt = swz & 7;        // 0..7
  const int mtile0 = mt * 256;
  const int ncol0 = nt * 128;

  const int l3 = lane >> 3;
  const int lc = lane & 7;
  const size_t laneOff = (size_t)l3 * K_DIM + (size_t)((lc ^ l3) << 3);
  const bf16_t* Ag = A + (size_t)(mtile0 + wave * 8) * K_DIM + laneOff;
  const bf16_t* Bg1 = B + (size_t)(1024 + ncol0 + wave * 8) * K_DIM + laneOff;
  const bf16_t* Bg2 = B + (size_t)(2048 + ncol0 + wave * 8) * K_DIM + laneOff;

  const int aRow = (wr * 128 + r16) * 128;   // bytes
  const int bRow = (wc * 32 + r16) * 128;    // within 128-row B panel
  const int cxor = (r16 & 7) * 16;
  const int qx = quad * 16;

  v4f acc1[8][2], acc2[8][2];
#pragma unroll
  for (int i = 0; i < 8; ++i)
#pragma unroll
    for (int j = 0; j < 2; ++j) { acc1[i][j] = (v4f)(0.0f); acc2[i][j] = (v4f)(0.0f); }

  v8bf afr[4];
  v8bf b1fr[2][2], b2fr[2][2];

#define STG2_A(d, q, kt) __builtin_amdgcn_global_load_lds( \
    (__attribute__((address_space(1))) void*)(Ag + (size_t)(q) * (64 * K_DIM) + (size_t)(kt) * 64), \
    (__attribute__((address_space(3))) void*)(smem + (d) * 32768 + (q) * 8192 + wave * 1024), 16, 0, 0)
#define STG2_B1(d, q, kt) __builtin_amdgcn_global_load_lds( \
    (__attribute__((address_space(1))) void*)(Bg1 + (size_t)(q) * (64 * K_DIM) + (size_t)(kt) * 64), \
    (__attribute__((address_space(3))) void*)(smem + 65536 + (d) * 32768 + (q) * 8192 + wave * 1024), 16, 0, 0)
#define STG2_B2(d, q, kt) __builtin_amdgcn_global_load_lds( \
    (__attribute__((address_space(1))) void*)(Bg2 + (size_t)(q) * (64 * K_DIM) + (size_t)(kt) * 64), \
    (__attribute__((address_space(3))) void*)(smem + 65536 + (d) * 32768 + 16384 + (q) * 8192 + wave * 1024), 16, 0, 0)
#define LDA2(d, i, kk) (*(const v8bf*)(smem + (d) * 32768 + aRow + (i) * 2048 + (((kk) * 64 + qx) ^ cxor)))
#define LDB21(d, j, kk) (*(const v8bf*)(smem + 65536 + (d) * 32768 + bRow + (j) * 2048 + (((kk) * 64 + qx) ^ cxor)))
#define LDB22(d, j, kk) (*(const v8bf*)(smem + 65536 + (d) * 32768 + 16384 + bRow + (j) * 2048 + (((kk) * 64 + qx) ^ cxor)))
#define RD2_A(d, ih, kk) { _Pragma("unroll") for (int ii = 0; ii < 4; ++ii) afr[ii] = LDA2(d, (ih) * 4 + ii, kk); }
#define RD2_B(d, kk) { _Pragma("unroll") for (int j = 0; j < 2; ++j) { b1fr[j][kk] = LDB21(d, j, kk); b2fr[j][kk] = LDB22(d, j, kk); } }
#define MM2(ih, kk) \
  __builtin_amdgcn_s_barrier(); \
  asm volatile("s_waitcnt lgkmcnt(0)" ::: "memory"); \
  __builtin_amdgcn_s_setprio(1); \
  { _Pragma("unroll") for (int ii = 0; ii < 4; ++ii) { _Pragma("unroll") for (int j = 0; j < 2; ++j) { \
      acc1[(ih) * 4 + ii][j] = __builtin_amdgcn_mfma_f32_16x16x32_bf16(afr[ii], b1fr[j][(kk)], acc1[(ih) * 4 + ii][j], 0, 0, 0); \
      acc2[(ih) * 4 + ii][j] = __builtin_amdgcn_mfma_f32_16x16x32_bf16(afr[ii], b2fr[j][(kk)], acc2[(ih) * 4 + ii][j], 0, 0, 0); } } } \
  __builtin_amdgcn_s_setprio(0);
#define BAR() __builtin_amdgcn_s_barrier()
#define WAITV(n) asm volatile("s_waitcnt vmcnt(" #n ")" ::: "memory")

  // ---- Prologue ----
  STG2_A(0, 0, 0); STG2_A(0, 1, 0); STG2_A(0, 2, 0); STG2_A(0, 3, 0);
  STG2_B1(0, 0, 0); STG2_B1(0, 1, 0); STG2_B2(0, 0, 0); STG2_B2(0, 1, 0);
  STG2_A(1, 0, 1); STG2_A(1, 2, 1); STG2_B1(1, 0, 1); STG2_B1(1, 1, 1);
  WAITV(4);
  BAR();

  for (int it = 0; it < 7; ++it) {
    const int t1 = 2 * it + 1, t2 = t1 + 1, t3 = t1 + 2;
    RD2_A(0, 0, 0); RD2_B(0, 0);
    STG2_B2(1, 0, t1); STG2_B2(1, 1, t1);
    MM2(0, 0); BAR();
    RD2_B(0, 1); RD2_A(0, 0, 1);
    STG2_A(1, 1, t1); STG2_A(1, 3, t1);
    MM2(0, 1); BAR();
    RD2_A(0, 1, 0);
    STG2_A(0, 0, t2); STG2_A(0, 2, t2);
    MM2(1, 0); BAR();
    RD2_A(0, 1, 1);
    STG2_B1(0, 0, t2); STG2_B1(0, 1, t2);
    MM2(1, 1); WAITV(4); BAR();
    RD2_A(1, 0, 0); RD2_B(1, 0);
    STG2_B2(0, 0, t2); STG2_B2(0, 1, t2);
    MM2(0, 0); BAR();
    RD2_B(1, 1); RD2_A(1, 0, 1);
    STG2_A(0, 1, t2); STG2_A(0, 3, t2);
    MM2(0, 1); BAR();
    RD2_A(1, 1, 0);
    STG2_A(1, 0, t3); STG2_A(1, 2, t3);
    MM2(1, 0); BAR();
    RD2_A(1, 1, 1);
    STG2_B1(1, 0, t3); STG2_B1(1, 1, t3);
    MM2(1, 1); WAITV(4); BAR();
  }
  // ---- Tail ----
  RD2_A(0, 0, 0); RD2_B(0, 0);
  STG2_B2(1, 0, 15); STG2_B2(1, 1, 15);
  MM2(0, 0); BAR();
  RD2_B(0, 1); RD2_A(0, 0, 1);
  STG2_A(1, 1, 15); STG2_A(1, 3, 15);
  MM2(0, 1); BAR();
  RD2_A(0, 1, 0); MM2(1, 0); BAR();
  RD2_A(0, 1, 1); MM2(1, 1); WAITV(0); BAR();

  // Lq prefetch: after the LAST counted WAITV — no subsequent vmcnt wait
  // counts these loads; their latency hides under the final 4 MFMA phases.
  const int gfb = mt * 8 + nt;
  const ushort4* Lq4 = (const ushort4*)Lp;
  ushort4 lfv[8][2];
#pragma unroll
  for (int i = 0; i < 8; ++i)
#pragma unroll
    for (int j = 0; j < 2; ++j)
      lfv[i][j] = Lq4[((size_t)gfb * 16 + i * 2 + j) * 512 + tid];

  RD2_A(1, 0, 0); RD2_B(1, 0); MM2(0, 0); BAR();
  RD2_B(1, 1); RD2_A(1, 0, 1); MM2(0, 1); BAR();
  RD2_A(1, 1, 0); MM2(1, 0); BAR();
  RD2_A(1, 1, 1); MM2(1, 1);

#undef STG2_A
#undef STG2_B1
#undef STG2_B2
#undef LDA2
#undef LDB21
#undef LDB22
#undef RD2_A
#undef RD2_B
#undef MM2
#undef BAR
#undef WAITV

  // ---- Fused final epilogue (compact store burst at exit, R2 rule). ----
  const int bidx = mtile0 >> 12;
  const int sub0 = (mtile0 & 4095) >> 5;
#pragma unroll
  for (int i = 0; i < 8; ++i) {
    const int subr = sub0 + wr * 4 + (i >> 1);
#pragma unroll
    for (int j = 0; j < 2; ++j) {
      const int col = ncol0 + wc * 32 + j * 16 + r16;
      const float pm = pmax[((size_t)bidx * NSUB + subr) * HIDDEN + col];
      const ushort4 q = lfv[i][j];
      const int row0 = mtile0 + wr * 128 + i * 16 + quad * 4;
      float m0 = fmaxf(pm, bf16_to_f32(q.x));
      float m1 = fmaxf(pm, bf16_to_f32(q.y));
      float m2 = fmaxf(pm, bf16_to_f32(q.z));
      float m3 = fmaxf(pm, bf16_to_f32(q.w));
      size_t idx = (size_t)row0 * HIDDEN + col;
      out[idx] = (m0 + acc2[i][j][0]) * m0 + acc1[i][j][0];
      out[idx + HIDDEN] = (m1 + acc2[i][j][1]) * m1 + acc1[i][j][1];
      out[idx + 2 * HIDDEN] = (m2 + acc2[i][j][2]) * m2 + acc1[i][j][2];
      out[idx + 3 * HIDDEN] = (m3 + acc2[i][j][3]) * m3 + acc1[i][j][3];
    }
  }
}

extern "C" void kernel_launch(void* const* d_in, const int* in_sizes, int n_in,
                              void* d_out, int out_size, void* d_ws, size_t ws_size,
                              hipStream_t stream) {
  const float* X = (const float*)d_in[0];
  const float* W0 = (const float*)d_in[1];
  const float* W1 = (const float*)d_in[2];
  const float* W2 = (const float*)d_in[3];
  float* out = (float*)d_out;

  char* ws = (char*)d_ws;
  unsigned short* Xb = (unsigned short*)ws;
  unsigned short* Wb = (unsigned short*)(ws + 33554432);
  unsigned short* Lp = (unsigned short*)(ws + 33554432 + 6291456);  // Lq
  float* cmax = (float*)(ws + 4 * 33554432 + 6291456);
  float* pmax = (float*)(ws + 4 * 33554432 + 6291456 + 2097152);

  convert_kernel<<<19456, 256, 0, stream>>>(X, W0, W1, W2, Xb, Wb);

  gemm_s_kernel<<<256, 512, 131072, stream>>>((const bf16_t*)Xb, (const bf16_t*)Wb,
                                              Lp, cmax);

  dim3 pgrid(4, BATCH);
  prefix_kernel<<<pgrid, 256, 0, stream>>>(cmax, pmax);

  gemm_f_kernel<<<512, 512, 131072, stream>>>((const bf16_t*)Xb, (const bf16_t*)Wb,
                                              Lp, pmax, out);
}